// Round 5
// baseline (72.283 us; speedup 1.0000x reference)
//
#include <hip/hip_runtime.h>
#include <hip/hip_bf16.h>
#include <stdint.h>

#define H 128
#define NU 100000
#define NI 50000

typedef __attribute__((ext_vector_type(8))) short short8;
typedef __attribute__((ext_vector_type(4))) float f32x4;

__device__ __forceinline__ uint16_t f2bf(float f) {
    uint32_t x = __float_as_uint(f);
    return (uint16_t)((x + 0x7fffu + ((x >> 16) & 1u)) >> 16);  // RNE
}
__device__ __forceinline__ uint32_t cvtpk(float lo, float hi) {
    uint32_t r;
    asm("v_cvt_pk_bf16_f32 %0, %1, %2" : "=v"(r) : "v"(lo), "v"(hi));
    return r;
}
__device__ __forceinline__ float cvt_ub0(uint32_t v) { float f; asm("v_cvt_f32_ubyte0 %0, %1" : "=v"(f) : "v"(v)); return f; }
__device__ __forceinline__ float cvt_ub1(uint32_t v) { float f; asm("v_cvt_f32_ubyte1 %0, %1" : "=v"(f) : "v"(v)); return f; }
__device__ __forceinline__ float cvt_ub2(uint32_t v) { float f; asm("v_cvt_f32_ubyte2 %0, %1" : "=v"(f) : "v"(v)); return f; }
__device__ __forceinline__ float cvt_ub3(uint32_t v) { float f; asm("v_cvt_f32_ubyte3 %0, %1" : "=v"(f) : "v"(v)); return f; }

// Swizzled byte offset into a [128][128] bf16 LDS tile (XOR bank swizzle).
__device__ __forceinline__ int lds_off(int row, int k) {
    return (row * 256 + k * 2) ^ ((row & 7) << 4);
}

// Tables are per-row-scaled biased int8, PERMUTED columns: byte position
// p = lr*8 + n0 holds column n0*16 + lr.  value = scale * (q - 128).
// Edge lane t reads bytes [t*8, t*8+8) = columns {j*16+t}, j=0..7.

// One-time: W1 [2H][H] f32 (k-major) -> Wt [2][H n][H k] bf16 (n-major).
__global__ __launch_bounds__(256) void wconv_kernel(
    const float* __restrict__ W1, uint16_t* __restrict__ Wt)
{
    __shared__ char lds[32768];
    const int half = blockIdx.x;
    const float* W = W1 + (size_t)half * H * H;
    uint16_t* Out = Wt + (size_t)half * H * H;
    const int tid = threadIdx.x;

    int n4 = (tid & 31) * 4;
    int k  = tid >> 5;
    #pragma unroll
    for (int p = 0; p < 16; ++p, k += 8) {
        f32x4 v = *(const f32x4*)(W + (size_t)k * H + n4);
        *(uint16_t*)(lds + lds_off(n4 + 0, k)) = f2bf(v.x);
        *(uint16_t*)(lds + lds_off(n4 + 1, k)) = f2bf(v.y);
        *(uint16_t*)(lds + lds_off(n4 + 2, k)) = f2bf(v.z);
        *(uint16_t*)(lds + lds_off(n4 + 3, k)) = f2bf(v.w);
    }
    __syncthreads();
    int n = tid >> 1;
    #pragma unroll
    for (int p = 0; p < 8; ++p) {
        int chunk = (tid & 1) * 8 + p;
        uint4 v = *(const uint4*)(lds + lds_off(n, chunk * 8));
        *(uint4*)(Out + (size_t)n * H + chunk * 8) = v;
    }
}

// Persistent projection: tile-stride loop; LDS W-tile re-staged only when the
// user/item half changes. Quantizes each output row to int8 + per-row scale.
__global__ __launch_bounds__(256) void proj_kernel(
    const float* __restrict__ z_user, const float* __restrict__ z_item,
    const uint16_t* __restrict__ Wt, const float* __restrict__ b1,
    uint8_t* __restrict__ U8, uint8_t* __restrict__ I8,
    float* __restrict__ Us, float* __restrict__ Is, int nub, int ntiles)
{
    __shared__ char lds[32768];
    const int tid = threadIdx.x;
    const int w  = tid >> 6;
    const int l  = tid & 63;
    const int lr = l & 15;
    const int lk = (l >> 4) * 8;
    int staged = -1;

    for (int tile = blockIdx.x; tile < ntiles; tile += gridDim.x) {
        int bid = tile;
        const float* Z; const uint16_t* Wth; uint8_t* Out8; float* Sc; int M; int half;
        if (bid < nub) { Z = z_user; Wth = Wt;         Out8 = U8; Sc = Us; M = NU; half = 0; }
        else { bid -= nub; Z = z_item; Wth = Wt + H*H; Out8 = I8; Sc = Is; M = NI; half = 1; }
        const int row0 = bid * 128;

        if (half != staged) {
            __syncthreads();   // protect prior tile's LDS reads
            int n = tid >> 1;
            #pragma unroll
            for (int p = 0; p < 8; ++p) {
                int chunk = (tid & 1) * 8 + p;
                uint4 v = *(const uint4*)(Wth + (size_t)n * H + chunk * 8);
                *(uint4*)(lds + lds_off(n, chunk * 8)) = v;
            }
            staged = half;
            __syncthreads();
        }

        int r0 = row0 + w * 32 + lr;
        int r1 = r0 + 16;
        const float* a0p = Z + (size_t)(r0 < M ? r0 : M - 1) * H;
        const float* a1p = Z + (size_t)(r1 < M ? r1 : M - 1) * H;

        f32x4 acc[2][8];
        #pragma unroll
        for (int m0 = 0; m0 < 2; ++m0)
            #pragma unroll
            for (int n0 = 0; n0 < 8; ++n0)
                acc[m0][n0] = (f32x4){0.f, 0.f, 0.f, 0.f};

        #pragma unroll
        for (int kk = 0; kk < 4; ++kk) {
            int kb = kk * 32 + lk;
            f32x4 v00 = *(const f32x4*)(a0p + kb);
            f32x4 v01 = *(const f32x4*)(a0p + kb + 4);
            f32x4 v10 = *(const f32x4*)(a1p + kb);
            f32x4 v11 = *(const f32x4*)(a1p + kb + 4);
            short8 a0, a1;
            uint32_t* A0 = (uint32_t*)&a0;
            uint32_t* A1 = (uint32_t*)&a1;
            A0[0] = cvtpk(v00.x, v00.y); A0[1] = cvtpk(v00.z, v00.w);
            A0[2] = cvtpk(v01.x, v01.y); A0[3] = cvtpk(v01.z, v01.w);
            A1[0] = cvtpk(v10.x, v10.y); A1[1] = cvtpk(v10.z, v10.w);
            A1[2] = cvtpk(v11.x, v11.y); A1[3] = cvtpk(v11.z, v11.w);
            #pragma unroll
            for (int n0 = 0; n0 < 8; ++n0) {
                short8 b = *(const short8*)(lds + lds_off(n0*16 + lr, kb));
                acc[0][n0] = __builtin_amdgcn_mfma_f32_16x16x32_bf16(a0, b, acc[0][n0], 0, 0, 0);
                acc[1][n0] = __builtin_amdgcn_mfma_f32_16x16x32_bf16(a1, b, acc[1][n0], 0, 0, 0);
            }
        }

        float b1v[8];
        #pragma unroll
        for (int n0 = 0; n0 < 8; ++n0) b1v[n0] = half ? b1[n0*16 + lr] : 0.f;

        // Quantizing epilogue. C/D: col = lane&15, row = (lane>>4)*4 + ri.
        const int rbase = row0 + w * 32;
        #pragma unroll
        for (int m0 = 0; m0 < 2; ++m0) {
            #pragma unroll
            for (int ri = 0; ri < 4; ++ri) {
                int gr = rbase + m0*16 + (l >> 4) * 4 + ri;
                float v[8];
                float am = 0.f;
                #pragma unroll
                for (int n0 = 0; n0 < 8; ++n0) {
                    v[n0] = acc[m0][n0][ri] + b1v[n0];
                    am = fmaxf(am, fabsf(v[n0]));
                }
                am = fmaxf(am, __shfl_xor(am, 1));
                am = fmaxf(am, __shfl_xor(am, 2));
                am = fmaxf(am, __shfl_xor(am, 4));
                am = fmaxf(am, __shfl_xor(am, 8));
                float s = am * (1.0f / 127.0f);
                float r = 127.0f / fmaxf(am, 1e-30f);
                uint32_t lo = 0, hi = 0;
                #pragma unroll
                for (int n0 = 0; n0 < 4; ++n0) {
                    uint32_t q8 = (uint32_t)fmaf(v[n0], r, 128.5f);  // 1..255
                    lo |= q8 << (8 * n0);
                }
                #pragma unroll
                for (int n0 = 4; n0 < 8; ++n0) {
                    uint32_t q8 = (uint32_t)fmaf(v[n0], r, 128.5f);
                    hi |= q8 << (8 * (n0 - 4));
                }
                if (gr < M) {
                    *(uint2*)(Out8 + (size_t)gr * H + lr * 8) = make_uint2(lo, hi);
                    if (lr == 0) Sc[gr] = s;
                }
            }
        }
    }
}

// out[e] = relu(su*(qU-128) + si*(qI-128)) . W2 + b2   (b1 pre-folded into I)
__device__ __forceinline__ float edge_dot8(uint2 u, uint2 i, float su, float si,
                                           const float* w2v) {
    float k = -128.0f * (su + si);
    float acc = 0.f, h;
    h = fmaf(su, cvt_ub0(u.x), fmaf(si, cvt_ub0(i.x), k)); acc = fmaf(fmaxf(h, 0.f), w2v[0], acc);
    h = fmaf(su, cvt_ub1(u.x), fmaf(si, cvt_ub1(i.x), k)); acc = fmaf(fmaxf(h, 0.f), w2v[1], acc);
    h = fmaf(su, cvt_ub2(u.x), fmaf(si, cvt_ub2(i.x), k)); acc = fmaf(fmaxf(h, 0.f), w2v[2], acc);
    h = fmaf(su, cvt_ub3(u.x), fmaf(si, cvt_ub3(i.x), k)); acc = fmaf(fmaxf(h, 0.f), w2v[3], acc);
    h = fmaf(su, cvt_ub0(u.y), fmaf(si, cvt_ub0(i.y), k)); acc = fmaf(fmaxf(h, 0.f), w2v[4], acc);
    h = fmaf(su, cvt_ub1(u.y), fmaf(si, cvt_ub1(i.y), k)); acc = fmaf(fmaxf(h, 0.f), w2v[5], acc);
    h = fmaf(su, cvt_ub2(u.y), fmaf(si, cvt_ub2(i.y), k)); acc = fmaf(fmaxf(h, 0.f), w2v[6], acc);
    h = fmaf(su, cvt_ub3(u.y), fmaf(si, cvt_ub3(i.y), k)); acc = fmaf(fmaxf(h, 0.f), w2v[7], acc);
    return acc;
}

__device__ __forceinline__ float group_reduce(float acc) {
    acc += __shfl_xor(acc, 8);
    acc += __shfl_xor(acc, 4);
    acc += __shfl_xor(acc, 2);
    acc += __shfl_xor(acc, 1);
    return acc;
}

__global__ __launch_bounds__(256) void edge_kernel(
    const uint8_t* __restrict__ U8, const uint8_t* __restrict__ I8,
    const float* __restrict__ Us, const float* __restrict__ Is,
    const int* __restrict__ row_idx, const int* __restrict__ col_idx,
    const float* __restrict__ W2, const float* __restrict__ b2p,
    float* __restrict__ out, int E)
{
    const int l = threadIdx.x & 63;
    const int g = l >> 4;
    const int t = l & 15;

    float w2v[8];
    #pragma unroll
    for (int j = 0; j < 8; ++j) w2v[j] = W2[j * 16 + t];  // permuted layout
    const float b2 = *b2p;

    const int wid = (int)((blockIdx.x * blockDim.x + threadIdx.x) >> 6);
    const int nw  = (int)((gridDim.x * blockDim.x) >> 6);
    const int stride = nw * 32;          // 8 edges per group, 4 groups per wave
    const int Emain = E & ~7;

    for (int e0 = wid * 32 + g * 8; e0 + 7 < E; e0 += stride) {
        int4 ra = *(const int4*)(row_idx + e0);
        int4 rb = *(const int4*)(row_idx + e0 + 4);
        int4 ca = *(const int4*)(col_idx + e0);
        int4 cb = *(const int4*)(col_idx + e0 + 4);
        int r[8], c[8];
        r[0]=ra.x; r[1]=ra.y; r[2]=ra.z; r[3]=ra.w;
        r[4]=rb.x; r[5]=rb.y; r[6]=rb.z; r[7]=rb.w;
        c[0]=ca.x; c[1]=ca.y; c[2]=ca.z; c[3]=ca.w;
        c[4]=cb.x; c[5]=cb.y; c[6]=cb.z; c[7]=cb.w;

        uint2 uu[8], ii[8];
        float su[8], si[8];
        #pragma unroll
        for (int q = 0; q < 8; ++q) {
            uu[q] = *(const uint2*)(U8 + (size_t)r[q] * H + t * 8);
            ii[q] = *(const uint2*)(I8 + (size_t)c[q] * H + t * 8);
        }
        #pragma unroll
        for (int q = 0; q < 8; ++q) { su[q] = Us[r[q]]; si[q] = Is[c[q]]; }

        float a[8];
        #pragma unroll
        for (int q = 0; q < 8; ++q)
            a[q] = group_reduce(edge_dot8(uu[q], ii[q], su[q], si[q], w2v));

        if (t == 0) {
            f32x4 o0; o0.x = a[0] + b2; o0.y = a[1] + b2; o0.z = a[2] + b2; o0.w = a[3] + b2;
            f32x4 o1; o1.x = a[4] + b2; o1.y = a[5] + b2; o1.z = a[6] + b2; o1.w = a[7] + b2;
            *(f32x4*)(out + e0)     = o0;
            *(f32x4*)(out + e0 + 4) = o1;
        }
    }
    // tail (E % 8 != 0) — not hit for E = 1M
    if (wid == 0 && g == 0) {
        for (int e = Emain; e < E; ++e) {
            int r = row_idx[e], c = col_idx[e];
            uint2 uv = *(const uint2*)(U8 + (size_t)r * H + t * 8);
            uint2 iv = *(const uint2*)(I8 + (size_t)c * H + t * 8);
            float acc = group_reduce(edge_dot8(uv, iv, Us[r], Is[c], w2v));
            if (t == 0) out[e] = acc + b2;
        }
    }
}

extern "C" void kernel_launch(void* const* d_in, const int* in_sizes, int n_in,
                              void* d_out, int out_size, void* d_ws, size_t ws_size,
                              hipStream_t stream) {
    const float* z_user = (const float*)d_in[0];
    const float* z_item = (const float*)d_in[1];
    const int*   row_idx = (const int*)d_in[2];
    const int*   col_idx = (const int*)d_in[3];
    const float* W1 = (const float*)d_in[4];
    const float* b1 = (const float*)d_in[5];
    const float* W2 = (const float*)d_in[6];
    const float* b2 = (const float*)d_in[7];
    float* out = (float*)d_out;
    const int E = in_sizes[2];

    uint8_t* U8 = (uint8_t*)d_ws;                   // 100000*128 = 12.8 MB
    uint8_t* I8 = U8 + (size_t)NU * H;              // 50000*128  =  6.4 MB
    float*   Us = (float*)(I8 + (size_t)NI * H);    // 400 KB
    float*   Is = Us + NU;                          // 200 KB
    uint16_t* Wt = (uint16_t*)(Is + NI);            // 64 KB (16B-aligned)

    const int nub = (NU + 127) / 128;  // 782
    const int nib = (NI + 127) / 128;  // 391
    const int ntiles = nub + nib;      // 1173
    wconv_kernel<<<2, 256, 0, stream>>>(W1, Wt);
    proj_kernel<<<512, 256, 0, stream>>>(z_user, z_item, Wt, b1, U8, I8, Us, Is, nub, ntiles);
    edge_kernel<<<2048, 256, 0, stream>>>(U8, I8, Us, Is, row_idx, col_idx, W2, b2, out, E);
}